// Round 8
// baseline (184.448 us; speedup 1.0000x reference)
//
#include <hip/hip_runtime.h>
#include <hip/hip_bf16.h>
#include <cstdint>
#include <cfloat>

#define NTOK 16384
#define DIN  1024
#define DOUT 1024
#define NEXP 8
#define RLORA 16
#define KTOT 1152          // DIN + NEXP*RLORA
#define SCALE_LORA 2.0f    // alpha/rank = 32/16

typedef __attribute__((ext_vector_type(8))) short bf16x8;
typedef __attribute__((ext_vector_type(4))) float f32x4;

__device__ __forceinline__ unsigned short f2bf(float f) {
  __hip_bfloat16 h = __float2bfloat16(f);
  unsigned short u;
  __builtin_memcpy(&u, &h, 2);
  return u;
}

__device__ __forceinline__ void gld_lds16(const void* g, void* l) {
  __builtin_amdgcn_global_load_lds((const __attribute__((address_space(1))) void*)g,
                                   (__attribute__((address_space(3))) void*)l,
                                   16, 0, 0);
}

// ---------------------------------------------------------------------------
// k_prep: fused preprocessing (R2 exact).
//   bid <  288 : transW  — WcatT[j][k] = [W_base; Bcat][k][j] bf16
//   bid <  320 : transA  — AcatT[e*16+r][d] = A[e][d][r] bf16
//   bid >= 320 : transG  — WgT[e][d] = Wg[d][e] fp32
// ---------------------------------------------------------------------------
__global__ __launch_bounds__(256) void k_prep(const float* __restrict__ Wb,
                                              const float* __restrict__ B,
                                              const float* __restrict__ A,
                                              const float* __restrict__ Wg,
                                              unsigned short* __restrict__ WcatT,
                                              unsigned short* __restrict__ AcatT,
                                              float* __restrict__ WgT) {
  __shared__ unsigned short Tbuf[256 * 17];   // 8704 B, covers 64*66 too
  const int bid = blockIdx.x;
  const int t = threadIdx.x;
  if (bid < 288) {
    unsigned short (*T)[66] = (unsigned short (*)[66])Tbuf;
    const int k0 = (bid % 18) * 64, j0 = (bid / 18) * 64;
#pragma unroll
    for (int p = 0; p < 4; ++p) {
      int kk = p * 16 + (t >> 4);
      int c4 = (t & 15) * 4;
      int k = k0 + kk;
      const float* src = (k < 1024) ? (Wb + (size_t)k * 1024) : (B + (size_t)(k - 1024) * 1024);
      float4 v = *(const float4*)(src + j0 + c4);
      T[kk][c4 + 0] = f2bf(v.x); T[kk][c4 + 1] = f2bf(v.y);
      T[kk][c4 + 2] = f2bf(v.z); T[kk][c4 + 3] = f2bf(v.w);
    }
    __syncthreads();
#pragma unroll
    for (int p = 0; p < 2; ++p) {
      int jj = p * 32 + (t >> 3);
      int kc = (t & 7) * 8;
      unsigned short buf[8];
#pragma unroll
      for (int i = 0; i < 8; ++i) buf[i] = T[kc + i][jj];
      uint4 u; __builtin_memcpy(&u, buf, 16);
      *(uint4*)(WcatT + (size_t)(j0 + jj) * KTOT + k0 + kc) = u;
    }
  } else if (bid < 320) {
    unsigned short (*T)[17] = (unsigned short (*)[17])Tbuf;
    const int e = (bid - 288) >> 2, d0 = ((bid - 288) & 3) * 256;
#pragma unroll
    for (int p = 0; p < 4; ++p) {
      int idx = p * 256 + t;
      int d = idx >> 2;
      int rr = (idx & 3) * 4;
      float4 v = *(const float4*)(A + (size_t)e * 16384 + (size_t)(d0 + d) * 16 + rr);
      T[d][rr + 0] = f2bf(v.x); T[d][rr + 1] = f2bf(v.y);
      T[d][rr + 2] = f2bf(v.z); T[d][rr + 3] = f2bf(v.w);
    }
    __syncthreads();
#pragma unroll
    for (int p = 0; p < 2; ++p) {
      int slot = p * 256 + t;
      int r = slot >> 5;
      int dc = (slot & 31) * 8;
      unsigned short buf[8];
#pragma unroll
      for (int i = 0; i < 8; ++i) buf[i] = T[dc + i][r];
      uint4 u; __builtin_memcpy(&u, buf, 16);
      *(uint4*)(AcatT + (size_t)(e * 16 + r) * 1024 + d0 + dc) = u;
    }
  } else {
    int d = (bid - 320) * 256 + t;
    float4 a = *(const float4*)(Wg + (size_t)d * 8);
    float4 b = *(const float4*)(Wg + (size_t)d * 8 + 4);
    WgT[0 * 1024 + d] = a.x; WgT[1 * 1024 + d] = a.y;
    WgT[2 * 1024 + d] = a.z; WgT[3 * 1024 + d] = a.w;
    WgT[4 * 1024 + d] = b.x; WgT[5 * 1024 + d] = b.y;
    WgT[6 * 1024 + d] = b.z; WgT[7 * 1024 + d] = b.w;
  }
}

// ---------------------------------------------------------------------------
// Router: one wave per TWO tokens, WgT coalesced reads (R2 exact).
// ---------------------------------------------------------------------------
__global__ __launch_bounds__(256) void k_router(const float* __restrict__ tokens,
                                                const float* __restrict__ WgT,
                                                float* __restrict__ out_logits,
                                                float* __restrict__ out_sel,
                                                float* __restrict__ out_w,
                                                unsigned short* __restrict__ Xcat,
                                                float4* __restrict__ gateinfo) {
  const int wid = threadIdx.x >> 6;
  const int lane = threadIdx.x & 63;
  const int t0 = (blockIdx.x * 4 + wid) * 2;

  float4 xa[4], xb[4];
  const float* x0 = tokens + (size_t)t0 * DIN;
  const float* x1 = x0 + DIN;
#pragma unroll
  for (int j = 0; j < 4; ++j) {
    xa[j] = *(const float4*)(x0 + j * 256 + lane * 4);
    xb[j] = *(const float4*)(x1 + j * 256 + lane * 4);
  }

#pragma unroll
  for (int tt = 0; tt < 2; ++tt) {
    unsigned short* xbp = Xcat + (size_t)(t0 + tt) * KTOT;
    const float4* xv = tt ? xb : xa;
#pragma unroll
    for (int j = 0; j < 4; ++j) {
      const float* xf = (const float*)&xv[j];
      unsigned short hb[4];
#pragma unroll
      for (int m = 0; m < 4; ++m) hb[m] = f2bf(xf[m]);
      uint2 u;
      __builtin_memcpy(&u, hb, 8);
      *(uint2*)(xbp + j * 256 + lane * 4) = u;
    }
  }

  float accA[8] = {0,0,0,0,0,0,0,0}, accB[8] = {0,0,0,0,0,0,0,0};
#pragma unroll
  for (int j = 0; j < 4; ++j) {
#pragma unroll
    for (int e = 0; e < 8; ++e) {
      float4 wv = *(const float4*)(WgT + (size_t)e * 1024 + j * 256 + lane * 4);
      accA[e] = fmaf(xa[j].x, wv.x, fmaf(xa[j].y, wv.y,
                fmaf(xa[j].z, wv.z, fmaf(xa[j].w, wv.w, accA[e]))));
      accB[e] = fmaf(xb[j].x, wv.x, fmaf(xb[j].y, wv.y,
                fmaf(xb[j].z, wv.z, fmaf(xb[j].w, wv.w, accB[e]))));
    }
  }
#pragma unroll
  for (int s = 1; s < 64; s <<= 1) {
#pragma unroll
    for (int e = 0; e < 8; ++e) {
      accA[e] += __shfl_xor(accA[e], s, 64);
      accB[e] += __shfl_xor(accB[e], s, 64);
    }
  }

#pragma unroll
  for (int tt = 0; tt < 2; ++tt) {
    const float* acc = tt ? accB : accA;
    int t = t0 + tt;
    float v0 = -FLT_MAX, v1 = -FLT_MAX;
    int i0 = -1, i1 = -1;
#pragma unroll
    for (int e = 0; e < 8; ++e) {
      float v = acc[e];
      if (v > v0) { v1 = v0; i1 = i0; v0 = v; i0 = e; }
      else if (v > v1) { v1 = v; i1 = e; }
    }
    float ex = expf(v1 - v0);
    float inv = 1.0f / (1.0f + ex);
    float w0 = inv, w1 = ex * inv;
    if (lane == 0) {
      float4* lg = (float4*)(out_logits + (size_t)t * 8);
      lg[0] = make_float4(acc[0], acc[1], acc[2], acc[3]);
      lg[1] = make_float4(acc[4], acc[5], acc[6], acc[7]);
      *(float2*)(out_sel + (size_t)t * 2) = make_float2((float)i0, (float)i1);
      *(float2*)(out_w + (size_t)t * 2) = make_float2(w0, w1);
      gateinfo[t] = make_float4((float)i0, (float)i1, w0 * SCALE_LORA, w1 * SCALE_LORA);
    }
  }
}

// ---------------------------------------------------------------------------
// H-GEMM + gating — NEW: T3-minimum pipelined dbuf. BM=BN=64, BK=64 kept
// (16 steps, fine-grained prefetch), LDS 2x(8+8)=32 KB, grid 512 (2
// blocks/CU, grid-limited). Per step: issue next-tile STAGE (4 gld_lds16/
// thread) BEFORE compute — the L3-latency Xcat loads (~500-900 cyc) fly
// under frag-reads + 8 MFMA; one vmcnt(0)+raw barrier per step (1-deep
// prefetch: all outstanding loads are next-tile's, so drain-to-0 is the
// minimal correct wait). Replaces the old stage->syncthreads(full drain,
// latency fully exposed)->compute shape. Same swizzle/frag/epilogue as R2.
// ---------------------------------------------------------------------------
__global__ __launch_bounds__(256) void k_hgemm(const unsigned short* __restrict__ Xg,
                                               const unsigned short* __restrict__ Ag,
                                               const float4* __restrict__ gateinfo,
                                               unsigned short* __restrict__ Xout) {
  constexpr int BK = 64;
  __shared__ alignas(16) unsigned short As[2][64 * BK];  // 2 x 8 KB
  __shared__ alignas(16) unsigned short Bs[2][64 * BK];  // 2 x 8 KB
  const int tid = threadIdx.x;
  const int lane = tid & 63;
  const int wid = tid >> 6;
  const int id = blockIdx.x;
  const int xcd = id & 7, s5 = id >> 3;
  const int n0 = (s5 & 1) * 64;
  const int m0 = (xcd * 32 + (s5 >> 1)) * 64;
  const int wm = (wid >> 1) * 32, wn = (wid & 1) * 32;
  const int quad = lane >> 4, r16 = lane & 15;

  f32x4 acc[2][2] = {};

  // Stage K-tile kt into slot d: 2 gld A + 2 gld B per thread.
  // chunk-XOR q = c ^ ((r>>1)&7), pre-swizzled source + linear LDS dest
  // (both-sides involution — R2-proven, 0 bank conflicts).
#define HST(d, kt)                                                            \
  {                                                                           \
    const int k0s = (kt) * BK;                                                \
    _Pragma("unroll")                                                         \
    for (int i_ = 0; i_ < 2; ++i_) {                                          \
      int s_ = i_ * 256 + tid;                                                \
      int r_ = s_ >> 3, c_ = s_ & 7;                                          \
      int q_ = c_ ^ ((r_ >> 1) & 7);                                          \
      gld_lds16(Xg + (size_t)(m0 + r_) * KTOT + k0s + q_ * 8,                 \
                (char*)As[d] + s_ * 16);                                      \
    }                                                                         \
    _Pragma("unroll")                                                         \
    for (int i_ = 0; i_ < 2; ++i_) {                                          \
      int s_ = i_ * 256 + tid;                                                \
      int r_ = s_ >> 3, c_ = s_ & 7;                                          \
      int q_ = c_ ^ ((r_ >> 1) & 7);                                          \
      gld_lds16(Ag + (size_t)(n0 + r_) * 1024 + k0s + q_ * 8,                 \
                (char*)Bs[d] + s_ * 16);                                      \
    }                                                                         \
  }

  HST(0, 0);
  asm volatile("s_waitcnt vmcnt(0)" ::: "memory");
  __builtin_amdgcn_s_barrier();

  int cur = 0;
  for (int t = 0; t < 16; ++t) {
    if (t < 15) HST(cur ^ 1, t + 1);   // prefetch issue BEFORE compute

#pragma unroll
    for (int h = 0; h < 2; ++h) {
      bf16x8 af[2], bfr[2];
#pragma unroll
      for (int mi = 0; mi < 2; ++mi) {
        int m = wm + mi * 16 + r16;
        int slot = m * 8 + ((h * 4 + quad) ^ ((m >> 1) & 7));
        af[mi] = *(const bf16x8*)((const char*)As[cur] + slot * 16);
      }
#pragma unroll
      for (int ni = 0; ni < 2; ++ni) {
        int n = wn + ni * 16 + r16;
        int slot = n * 8 + ((h * 4 + quad) ^ ((n >> 1) & 7));
        bfr[ni] = *(const bf16x8*)((const char*)Bs[cur] + slot * 16);
      }
#pragma unroll
      for (int mi = 0; mi < 2; ++mi)
#pragma unroll
        for (int ni = 0; ni < 2; ++ni)
          acc[mi][ni] = __builtin_amdgcn_mfma_f32_16x16x32_bf16(af[mi], bfr[ni], acc[mi][ni], 0, 0, 0);
    }
    // This step's ds_reads completed (MFMA register deps force lgkm waits
    // before the barrier); drain next-tile loads, then one barrier.
    asm volatile("s_waitcnt vmcnt(0)" ::: "memory");
    __builtin_amdgcn_s_barrier();
    cur ^= 1;
  }
#undef HST

#pragma unroll
  for (int mi = 0; mi < 2; ++mi)
#pragma unroll
    for (int r = 0; r < 4; ++r) {
      int row = m0 + wm + mi * 16 + quad * 4 + r;
      float4 gi = gateinfo[row];
      int ie0 = (int)gi.x, ie1 = (int)gi.y;
#pragma unroll
      for (int ni = 0; ni < 2; ++ni) {
        int c = n0 + wn + ni * 16 + r16;
        int e = c >> 4;
        float h = acc[mi][ni][r];
        float v = (e == ie0) ? gi.z * h : ((e == ie1) ? gi.w * h : 0.f);
        Xout[(size_t)row * KTOT + 1024 + c] = f2bf(v);
      }
    }
}

// ---------------------------------------------------------------------------
// Main GEMM (R7 exact, measured-best 45.7 µs): 128x128, BK=64, 4 waves,
// 32 KB single-buffered LDS, 2-barrier loop, grid 1024, ~4 blocks/CU —
// cross-block wave overlap hides write tail / prologue / barrier drains.
// ---------------------------------------------------------------------------
__global__ __launch_bounds__(256, 4) void k_gemm_main(const unsigned short* __restrict__ Xg,
                                                      const unsigned short* __restrict__ Wgm,
                                                      float* __restrict__ C) {
  __shared__ alignas(16) unsigned short As[128 * 64];  // 16 KB
  __shared__ alignas(16) unsigned short Bs[128 * 64];  // 16 KB
  const int tid = threadIdx.x;
  const int lane = tid & 63;
  const int wid = tid >> 6;
  const int id = blockIdx.x;
  const int gid = (id & 7) * 128 + (id >> 3);  // XCD chunked, bijective (1024%8==0)
  const int m0 = (gid >> 3) * 128;             // 128 m-tiles
  const int n0 = (gid & 7) * 128;              // 8 n-tiles
  const int wm = (wid >> 1) * 64, wn = (wid & 1) * 64;
  const int quad = lane >> 4, r16 = lane & 15;

  f32x4 acc[4][4] = {};

  for (int kt = 0; kt < 18; ++kt) {
    const int k0 = kt * 64;
#pragma unroll
    for (int i = 0; i < 4; ++i) {
      int s = i * 256 + tid;
      int r = s >> 3, c = s & 7;
      int q = c ^ ((r >> 1) & 7);
      gld_lds16(Xg + (size_t)(m0 + r) * KTOT + k0 + q * 8, (char*)As + s * 16);
    }
#pragma unroll
    for (int i = 0; i < 4; ++i) {
      int s = i * 256 + tid;
      int r = s >> 3, c = s & 7;
      int q = c ^ ((r >> 1) & 7);
      gld_lds16(Wgm + (size_t)(n0 + r) * KTOT + k0 + q * 8, (char*)Bs + s * 16);
    }
    __syncthreads();   // drains vmcnt(0) — covered by other resident blocks

#pragma unroll
    for (int h = 0; h < 2; ++h) {
      bf16x8 af[4], bfr[4];
#pragma unroll
      for (int mi = 0; mi < 4; ++mi) {
        int m = wm + mi * 16 + r16;
        int slot = m * 8 + ((h * 4 + quad) ^ ((m >> 1) & 7));
        af[mi] = *(const bf16x8*)((const char*)As + slot * 16);
      }
#pragma unroll
      for (int ni = 0; ni < 4; ++ni) {
        int n = wn + ni * 16 + r16;
        int slot = n * 8 + ((h * 4 + quad) ^ ((n >> 1) & 7));
        bfr[ni] = *(const bf16x8*)((const char*)Bs + slot * 16);
      }
#pragma unroll
      for (int mi = 0; mi < 4; ++mi)
#pragma unroll
        for (int ni = 0; ni < 4; ++ni)
          acc[mi][ni] = __builtin_amdgcn_mfma_f32_16x16x32_bf16(af[mi], bfr[ni], acc[mi][ni], 0, 0, 0);
    }
    __syncthreads();
  }

  // C/D layout: col = lane&15, row = quad*4 + reg  [m89/m91]
#pragma unroll
  for (int mi = 0; mi < 4; ++mi)
#pragma unroll
    for (int ni = 0; ni < 4; ++ni)
#pragma unroll
      for (int r = 0; r < 4; ++r) {
        int row = m0 + wm + mi * 16 + quad * 4 + r;
        int cc = n0 + wn + ni * 16 + r16;
        C[(size_t)row * 1024 + cc] = acc[mi][ni][r];
      }
}

// ---------------------------------------------------------------------------
extern "C" void kernel_launch(void* const* d_in, const int* in_sizes, int n_in,
                              void* d_out, int out_size, void* d_ws, size_t ws_size,
                              hipStream_t stream) {
  const float* tokens = (const float*)d_in[0];
  const float* Wb     = (const float*)d_in[1];
  const float* A      = (const float*)d_in[2];
  const float* B      = (const float*)d_in[3];
  const float* Wg     = (const float*)d_in[4];
  float* out = (float*)d_out;

  char* ws = (char*)d_ws;
  unsigned short* Xcat  = (unsigned short*)(ws);                 // [16384][1152] bf16  37748736 B
  unsigned short* WcatT = (unsigned short*)(ws + 37748736);      // [1024][1152] bf16    2359296 B
  unsigned short* AcatT = (unsigned short*)(ws + 40108032);      // [128][1024] bf16      262144 B
  float4*         ginfo = (float4*)(ws + 40370176);              // [16384] float4       262144 B
  float*          WgT   = (float*)(ws + 40632320);               // [8][1024] fp32         32768 B

  float* out_logits = out + (size_t)16384 * 1024;
  float* out_sel    = out_logits + (size_t)16384 * 8;
  float* out_w      = out_sel + (size_t)16384 * 2;

  k_prep<<<dim3(324), dim3(256), 0, stream>>>(Wb, B, A, Wg, WcatT, AcatT, WgT);
  k_router<<<dim3(2048), dim3(256), 0, stream>>>(tokens, WgT, out_logits, out_sel, out_w, Xcat, ginfo);
  k_hgemm<<<dim3(512), dim3(256), 0, stream>>>(Xcat, AcatT, ginfo, Xcat);
  k_gemm_main<<<dim3(1024), dim3(256), 0, stream>>>(Xcat, WcatT, out);
}

// Round 9
// 177.400 us; speedup vs baseline: 1.0397x; 1.0397x over previous
//
#include <hip/hip_runtime.h>
#include <hip/hip_bf16.h>
#include <cstdint>
#include <cfloat>

#define NTOK 16384
#define DIN  1024
#define DOUT 1024
#define NEXP 8
#define RLORA 16
#define KTOT 1152          // DIN + NEXP*RLORA
#define SCALE_LORA 2.0f    // alpha/rank = 32/16

typedef __attribute__((ext_vector_type(8))) short bf16x8;
typedef __attribute__((ext_vector_type(4))) float f32x4;

__device__ __forceinline__ unsigned short f2bf(float f) {
  __hip_bfloat16 h = __float2bfloat16(f);
  unsigned short u;
  __builtin_memcpy(&u, &h, 2);
  return u;
}

__device__ __forceinline__ void gld_lds16(const void* g, void* l) {
  __builtin_amdgcn_global_load_lds((const __attribute__((address_space(1))) void*)g,
                                   (__attribute__((address_space(3))) void*)l,
                                   16, 0, 0);
}

// ---------------------------------------------------------------------------
// k_rp: prep + router in ONE launch (grid 2368). Blocks are INDEPENDENT —
// no intra-launch data deps (router no longer reads a prep output):
//   bid <  288 : transW  — WcatT[j][k] = [W_base; Bcat][k][j] bf16 (R2 exact)
//   bid <  320 : transA  — AcatT[e*16+r][d] = A[e][d][r] bf16 (R2 exact)
//   bid >= 320 : router  — builds WgT in LDS itself: cooperative COALESCED
//                load of Wg (32 contiguous floats/thread) transposed into
//                32 KB LDS, then float4 reads at lane*16B (canonical
//                conflict-free pattern). Same wv values in the same fmaf
//                order as the R2 WgT router -> bitwise-identical logits.
// LDS 32 KB -> 5 blocks/CU on router blocks (20 waves/CU, BW-saturating);
// transG kernel work deleted; prep runs in the router's shadow.
// ---------------------------------------------------------------------------
__global__ __launch_bounds__(256) void k_rp(const float* __restrict__ tokens,
                                            const float* __restrict__ Wg,
                                            const float* __restrict__ Wb,
                                            const float* __restrict__ B,
                                            const float* __restrict__ A,
                                            float* __restrict__ out_logits,
                                            float* __restrict__ out_sel,
                                            float* __restrict__ out_w,
                                            unsigned short* __restrict__ Xcat,
                                            float4* __restrict__ gateinfo,
                                            unsigned short* __restrict__ WcatT,
                                            unsigned short* __restrict__ AcatT) {
  __shared__ alignas(16) char smem[32768];    // union: prep Tbuf / router WgT
  const int bid = blockIdx.x;
  const int t = threadIdx.x;

  if (bid < 288) {                            // ---- transW (R2 exact) ----
    unsigned short (*T)[66] = (unsigned short (*)[66])smem;
    const int k0 = (bid % 18) * 64, j0 = (bid / 18) * 64;
#pragma unroll
    for (int p = 0; p < 4; ++p) {
      int kk = p * 16 + (t >> 4);
      int c4 = (t & 15) * 4;
      int k = k0 + kk;
      const float* src = (k < 1024) ? (Wb + (size_t)k * 1024) : (B + (size_t)(k - 1024) * 1024);
      float4 v = *(const float4*)(src + j0 + c4);
      T[kk][c4 + 0] = f2bf(v.x); T[kk][c4 + 1] = f2bf(v.y);
      T[kk][c4 + 2] = f2bf(v.z); T[kk][c4 + 3] = f2bf(v.w);
    }
    __syncthreads();
#pragma unroll
    for (int p = 0; p < 2; ++p) {
      int jj = p * 32 + (t >> 3);
      int kc = (t & 7) * 8;
      unsigned short buf[8];
#pragma unroll
      for (int i = 0; i < 8; ++i) buf[i] = T[kc + i][jj];
      uint4 u; __builtin_memcpy(&u, buf, 16);
      *(uint4*)(WcatT + (size_t)(j0 + jj) * KTOT + k0 + kc) = u;
    }
    return;
  }
  if (bid < 320) {                            // ---- transA (R2 exact) ----
    unsigned short (*T)[17] = (unsigned short (*)[17])smem;
    const int e = (bid - 288) >> 2, d0 = ((bid - 288) & 3) * 256;
#pragma unroll
    for (int p = 0; p < 4; ++p) {
      int idx = p * 256 + t;
      int d = idx >> 2;
      int rr = (idx & 3) * 4;
      float4 v = *(const float4*)(A + (size_t)e * 16384 + (size_t)(d0 + d) * 16 + rr);
      T[d][rr + 0] = f2bf(v.x); T[d][rr + 1] = f2bf(v.y);
      T[d][rr + 2] = f2bf(v.z); T[d][rr + 3] = f2bf(v.w);
    }
    __syncthreads();
#pragma unroll
    for (int p = 0; p < 2; ++p) {
      int slot = p * 256 + t;
      int r = slot >> 5;
      int dc = (slot & 31) * 8;
      unsigned short buf[8];
#pragma unroll
      for (int i = 0; i < 8; ++i) buf[i] = T[dc + i][r];
      uint4 u; __builtin_memcpy(&u, buf, 16);
      *(uint4*)(AcatT + (size_t)(e * 16 + r) * 1024 + d0 + dc) = u;
    }
    return;
  }

  // ---- router (R2 numeric path; WgT built in LDS) ----
  float* WgTl = (float*)smem;                 // [8][1024] fp32 = 32 KB
  {
    // thread t loads Wg floats [t*32, t*32+32) — fully coalesced — and
    // scatters transposed into LDS (one-time ~8-way write conflict, trivial).
#pragma unroll
    for (int i = 0; i < 8; ++i) {
      int f0 = t * 32 + i * 4;
      float4 v = *(const float4*)(Wg + f0);
      WgTl[(size_t)((f0 + 0) & 7) * 1024 + ((f0 + 0) >> 3)] = v.x;
      WgTl[(size_t)((f0 + 1) & 7) * 1024 + ((f0 + 1) >> 3)] = v.y;
      WgTl[(size_t)((f0 + 2) & 7) * 1024 + ((f0 + 2) >> 3)] = v.z;
      WgTl[(size_t)((f0 + 3) & 7) * 1024 + ((f0 + 3) >> 3)] = v.w;
    }
  }
  __syncthreads();

  const int wid = t >> 6;
  const int lane = t & 63;
  const int t0 = ((bid - 320) * 4 + wid) * 2;

  float4 xa[4], xb[4];
  const float* x0 = tokens + (size_t)t0 * DIN;
  const float* x1 = x0 + DIN;
#pragma unroll
  for (int j = 0; j < 4; ++j) {
    xa[j] = *(const float4*)(x0 + j * 256 + lane * 4);
    xb[j] = *(const float4*)(x1 + j * 256 + lane * 4);
  }

#pragma unroll
  for (int tt = 0; tt < 2; ++tt) {
    unsigned short* xbp = Xcat + (size_t)(t0 + tt) * KTOT;
    const float4* xv = tt ? xb : xa;
#pragma unroll
    for (int j = 0; j < 4; ++j) {
      const float* xf = (const float*)&xv[j];
      unsigned short hb[4];
#pragma unroll
      for (int m = 0; m < 4; ++m) hb[m] = f2bf(xf[m]);
      uint2 u;
      __builtin_memcpy(&u, hb, 8);
      *(uint2*)(xbp + j * 256 + lane * 4) = u;
    }
  }

  float accA[8] = {0,0,0,0,0,0,0,0}, accB[8] = {0,0,0,0,0,0,0,0};
#pragma unroll
  for (int j = 0; j < 4; ++j) {
#pragma unroll
    for (int e = 0; e < 8; ++e) {
      float4 wv = *(const float4*)(WgTl + (size_t)e * 1024 + j * 256 + lane * 4);
      accA[e] = fmaf(xa[j].x, wv.x, fmaf(xa[j].y, wv.y,
                fmaf(xa[j].z, wv.z, fmaf(xa[j].w, wv.w, accA[e]))));
      accB[e] = fmaf(xb[j].x, wv.x, fmaf(xb[j].y, wv.y,
                fmaf(xb[j].z, wv.z, fmaf(xb[j].w, wv.w, accB[e]))));
    }
  }
#pragma unroll
  for (int s = 1; s < 64; s <<= 1) {
#pragma unroll
    for (int e = 0; e < 8; ++e) {
      accA[e] += __shfl_xor(accA[e], s, 64);
      accB[e] += __shfl_xor(accB[e], s, 64);
    }
  }

#pragma unroll
  for (int tt = 0; tt < 2; ++tt) {
    const float* acc = tt ? accB : accA;
    int tk = t0 + tt;
    float v0 = -FLT_MAX, v1 = -FLT_MAX;
    int i0 = -1, i1 = -1;
#pragma unroll
    for (int e = 0; e < 8; ++e) {
      float v = acc[e];
      if (v > v0) { v1 = v0; i1 = i0; v0 = v; i0 = e; }
      else if (v > v1) { v1 = v; i1 = e; }
    }
    float ex = expf(v1 - v0);
    float inv = 1.0f / (1.0f + ex);
    float w0 = inv, w1 = ex * inv;
    if (lane == 0) {
      float4* lg = (float4*)(out_logits + (size_t)tk * 8);
      lg[0] = make_float4(acc[0], acc[1], acc[2], acc[3]);
      lg[1] = make_float4(acc[4], acc[5], acc[6], acc[7]);
      *(float2*)(out_sel + (size_t)tk * 2) = make_float2((float)i0, (float)i1);
      *(float2*)(out_w + (size_t)tk * 2) = make_float2(w0, w1);
      gateinfo[tk] = make_float4((float)i0, (float)i1, w0 * SCALE_LORA, w1 * SCALE_LORA);
    }
  }
}

// ---------------------------------------------------------------------------
// H-GEMM + gating (R2 exact — measured-best hgemm; R8's dbuf variant
// regressed +4 µs and is reverted). BM=64, BN=64, BK=64, grid 512.
// ---------------------------------------------------------------------------
__global__ __launch_bounds__(256) void k_hgemm(const unsigned short* __restrict__ Xg,
                                               const unsigned short* __restrict__ Ag,
                                               const float4* __restrict__ gateinfo,
                                               unsigned short* __restrict__ Xout) {
  constexpr int BK = 64;
  __shared__ alignas(16) unsigned short As[64 * BK];
  __shared__ alignas(16) unsigned short Bs[64 * BK];
  const int tid = threadIdx.x;
  const int lane = tid & 63;
  const int wid = tid >> 6;
  const int id = blockIdx.x;
  const int xcd = id & 7, s5 = id >> 3;
  const int n0 = (s5 & 1) * 64;
  const int m0 = (xcd * 32 + (s5 >> 1)) * 64;
  const int wm = (wid >> 1) * 32, wn = (wid & 1) * 32;
  const int quad = lane >> 4, r16 = lane & 15;

  f32x4 acc[2][2] = {};

  for (int k0 = 0; k0 < 1024; k0 += BK) {
#pragma unroll
    for (int i = 0; i < 2; ++i) {
      int s = i * 256 + tid;
      int r = s >> 3, c = s & 7;
      int q = c ^ ((r >> 1) & 7);
      gld_lds16(Xg + (size_t)(m0 + r) * KTOT + k0 + q * 8, (char*)As + s * 16);
    }
#pragma unroll
    for (int i = 0; i < 2; ++i) {
      int s = i * 256 + tid;
      int r = s >> 3, c = s & 7;
      int q = c ^ ((r >> 1) & 7);
      gld_lds16(Ag + (size_t)(n0 + r) * 1024 + k0 + q * 8, (char*)Bs + s * 16);
    }
    __syncthreads();

#pragma unroll
    for (int h = 0; h < 2; ++h) {
      bf16x8 af[2], bfr[2];
#pragma unroll
      for (int mi = 0; mi < 2; ++mi) {
        int m = wm + mi * 16 + r16;
        int slot = m * 8 + ((h * 4 + quad) ^ ((m >> 1) & 7));
        af[mi] = *(const bf16x8*)((const char*)As + slot * 16);
      }
#pragma unroll
      for (int ni = 0; ni < 2; ++ni) {
        int n = wn + ni * 16 + r16;
        int slot = n * 8 + ((h * 4 + quad) ^ ((n >> 1) & 7));
        bfr[ni] = *(const bf16x8*)((const char*)Bs + slot * 16);
      }
#pragma unroll
      for (int mi = 0; mi < 2; ++mi)
#pragma unroll
        for (int ni = 0; ni < 2; ++ni)
          acc[mi][ni] = __builtin_amdgcn_mfma_f32_16x16x32_bf16(af[mi], bfr[ni], acc[mi][ni], 0, 0, 0);
    }
    __syncthreads();
  }

#pragma unroll
  for (int mi = 0; mi < 2; ++mi)
#pragma unroll
    for (int r = 0; r < 4; ++r) {
      int row = m0 + wm + mi * 16 + quad * 4 + r;
      float4 gi = gateinfo[row];
      int ie0 = (int)gi.x, ie1 = (int)gi.y;
#pragma unroll
      for (int ni = 0; ni < 2; ++ni) {
        int c = n0 + wn + ni * 16 + r16;
        int e = c >> 4;
        float h = acc[mi][ni][r];
        float v = (e == ie0) ? gi.z * h : ((e == ie1) ? gi.w * h : 0.f);
        Xout[(size_t)row * KTOT + 1024 + c] = f2bf(v);
      }
    }
}

// ---------------------------------------------------------------------------
// Main GEMM (R7 exact, measured-best 45.7 µs): 128x128, BK=64, 4 waves,
// 32 KB single-buffered LDS, 2-barrier loop, grid 1024, ~4 blocks/CU —
// cross-block wave overlap hides write tail / prologue / barrier drains.
// ---------------------------------------------------------------------------
__global__ __launch_bounds__(256, 4) void k_gemm_main(const unsigned short* __restrict__ Xg,
                                                      const unsigned short* __restrict__ Wgm,
                                                      float* __restrict__ C) {
  __shared__ alignas(16) unsigned short As[128 * 64];  // 16 KB
  __shared__ alignas(16) unsigned short Bs[128 * 64];  // 16 KB
  const int tid = threadIdx.x;
  const int lane = tid & 63;
  const int wid = tid >> 6;
  const int id = blockIdx.x;
  const int gid = (id & 7) * 128 + (id >> 3);  // XCD chunked, bijective (1024%8==0)
  const int m0 = (gid >> 3) * 128;             // 128 m-tiles
  const int n0 = (gid & 7) * 128;              // 8 n-tiles
  const int wm = (wid >> 1) * 64, wn = (wid & 1) * 64;
  const int quad = lane >> 4, r16 = lane & 15;

  f32x4 acc[4][4] = {};

  for (int kt = 0; kt < 18; ++kt) {
    const int k0 = kt * 64;
#pragma unroll
    for (int i = 0; i < 4; ++i) {
      int s = i * 256 + tid;
      int r = s >> 3, c = s & 7;
      int q = c ^ ((r >> 1) & 7);
      gld_lds16(Xg + (size_t)(m0 + r) * KTOT + k0 + q * 8, (char*)As + s * 16);
    }
#pragma unroll
    for (int i = 0; i < 4; ++i) {
      int s = i * 256 + tid;
      int r = s >> 3, c = s & 7;
      int q = c ^ ((r >> 1) & 7);
      gld_lds16(Wgm + (size_t)(n0 + r) * KTOT + k0 + q * 8, (char*)Bs + s * 16);
    }
    __syncthreads();   // drains vmcnt(0) — covered by other resident blocks

#pragma unroll
    for (int h = 0; h < 2; ++h) {
      bf16x8 af[4], bfr[4];
#pragma unroll
      for (int mi = 0; mi < 4; ++mi) {
        int m = wm + mi * 16 + r16;
        int slot = m * 8 + ((h * 4 + quad) ^ ((m >> 1) & 7));
        af[mi] = *(const bf16x8*)((const char*)As + slot * 16);
      }
#pragma unroll
      for (int ni = 0; ni < 4; ++ni) {
        int n = wn + ni * 16 + r16;
        int slot = n * 8 + ((h * 4 + quad) ^ ((n >> 1) & 7));
        bfr[ni] = *(const bf16x8*)((const char*)Bs + slot * 16);
      }
#pragma unroll
      for (int mi = 0; mi < 4; ++mi)
#pragma unroll
        for (int ni = 0; ni < 4; ++ni)
          acc[mi][ni] = __builtin_amdgcn_mfma_f32_16x16x32_bf16(af[mi], bfr[ni], acc[mi][ni], 0, 0, 0);
    }
    __syncthreads();
  }

  // C/D layout: col = lane&15, row = quad*4 + reg  [m89/m91]
#pragma unroll
  for (int mi = 0; mi < 4; ++mi)
#pragma unroll
    for (int ni = 0; ni < 4; ++ni)
#pragma unroll
      for (int r = 0; r < 4; ++r) {
        int row = m0 + wm + mi * 16 + quad * 4 + r;
        int cc = n0 + wn + ni * 16 + r16;
        C[(size_t)row * 1024 + cc] = acc[mi][ni][r];
      }
}

// ---------------------------------------------------------------------------
extern "C" void kernel_launch(void* const* d_in, const int* in_sizes, int n_in,
                              void* d_out, int out_size, void* d_ws, size_t ws_size,
                              hipStream_t stream) {
  const float* tokens = (const float*)d_in[0];
  const float* Wb     = (const float*)d_in[1];
  const float* A      = (const float*)d_in[2];
  const float* B      = (const float*)d_in[3];
  const float* Wg     = (const float*)d_in[4];
  float* out = (float*)d_out;

  char* ws = (char*)d_ws;
  unsigned short* Xcat  = (unsigned short*)(ws);                 // [16384][1152] bf16  37748736 B
  unsigned short* WcatT = (unsigned short*)(ws + 37748736);      // [1024][1152] bf16    2359296 B
  unsigned short* AcatT = (unsigned short*)(ws + 40108032);      // [128][1024] bf16      262144 B
  float4*         ginfo = (float4*)(ws + 40370176);              // [16384] float4       262144 B

  float* out_logits = out + (size_t)16384 * 1024;
  float* out_sel    = out_logits + (size_t)16384 * 8;
  float* out_w      = out_sel + (size_t)16384 * 2;

  k_rp<<<dim3(2368), dim3(256), 0, stream>>>(tokens, Wg, Wb, B, A,
                                             out_logits, out_sel, out_w,
                                             Xcat, ginfo, WcatT, AcatT);
  k_hgemm<<<dim3(512), dim3(256), 0, stream>>>(Xcat, AcatT, ginfo, Xcat);
  k_gemm_main<<<dim3(1024), dim3(256), 0, stream>>>(Xcat, WcatT, out);
}